// Round 8
// baseline (112.507 us; speedup 1.0000x reference)
//
#include <hip/hip_runtime.h>

// SparseDopplerAttention on gfx950 — R10 (base = R7/R9 at ~31.7 us).
// Identity: out[q] = (sum_k P[q,k]*vsum[k]) / (sum_k P[q,k]),
//   vsum[k] = x[k] . colsum(Wv) + sum(bv) (fp32) — V/PV GEMMs eliminated.
// Evidence chain: occupancy x3 = no effect; R9 latency-hiding/VALU-packing =
// exactly neutral; R6-k2 (2 MB LDS/CU) ~2x R7's Phase B (1 MB/CU); R8 (same
// 1 MB/CU, different occupancy) ~= R7.  => Phase B time tracks LDS bytes/CU.
// R10 halves them: waves 0-7 each attend 64 queries (own 32 + partner w+8's 32,
// Q fragments read from the partner's LDS transpose scratch before K overwrites
// it), waves 8-15 idle during Phase B (idle waves use no LDS BW). Build phase
// (x, vsum, Q GEMM, K GEMM) remains 16-wave parallel and byte-identical.
// Phase-B K-tile traffic: 16x64KB=1MB -> 8x64KB=512KB per CU.

#define SCALE 0.18033688011112042f   // log2(e)/8

typedef __bf16 bf16;
typedef bf16 v4bf __attribute__((ext_vector_type(4)));
typedef bf16 v8bf __attribute__((ext_vector_type(8)));
typedef float v4f __attribute__((ext_vector_type(4)));
typedef float v2f __attribute__((ext_vector_type(2)));

__device__ __forceinline__ v8bf pk8(float4 a, float4 b) {
    v8bf r;
    r[0] = (bf16)a.x; r[1] = (bf16)a.y; r[2] = (bf16)a.z; r[3] = (bf16)a.w;
    r[4] = (bf16)b.x; r[5] = (bf16)b.y; r[6] = (bf16)b.z; r[7] = (bf16)b.w;
    return r;
}
__device__ __forceinline__ float d4(float4 a, v4f w) {
    return a.x * w[0] + a.y * w[1] + a.z * w[2] + a.w * w[3];
}

__global__ __launch_bounds__(1024, 4)
void sda_kernel(const float* __restrict__ power,
                const int*   __restrict__ ele_i,
                const int*   __restrict__ azi_i,
                const float* __restrict__ ele_t,
                const float* __restrict__ azi_t,
                const float* __restrict__ Wq, const float* __restrict__ bq,
                const float* __restrict__ Wk, const float* __restrict__ bk,
                const float* __restrict__ Wv, const float* __restrict__ bv,
                float* __restrict__ out)
{
    extern __shared__ char smem[];
    char*  Kb   = smem;                      // 64 KB: K [key][dim] bf16, 128 B rows, blk16 ^= key&7
    float* vsum = (float*)(smem + 65536);    // 512 f32
    float* wvs  = (float*)(smem + 67584);    // 96 col-sums of Wv + [96]=sum(bv)
    bf16*  WqL  = (bf16*)(smem + 68096);     // 12 KB: Wq bf16 row-major [64][96]
    bf16*  WkL  = (bf16*)(smem + 80384);     // 12 KB: Wk bf16 row-major [64][96]
    float* bqL  = (float*)(smem + 92672);    // 64 f32
    float* bkL  = (float*)(smem + 92928);    // 64 f32
    float* pbuf = (float*)smem;              // prologue-only: 832 f32 inside Kb

    const int tid  = threadIdx.x;
    const int wave = tid >> 6;
    const int lane = tid & 63;
    const int l15  = lane & 15;
    const int quad = lane >> 4;
    const int rowbase = blockIdx.x * 512 + wave * 32;   // this wave's 32 build rows

    // ---- issue cold loads first: indices -> power rows -> table gathers ----
    int IE[2], IA[2];
#pragma unroll
    for (int mt = 0; mt < 2; mt++) {
        int row = rowbase + mt * 16 + l15;
        IE[mt] = ele_i[row];
        IA[mt] = azi_i[row];
    }
    float4 A[2][4];
#pragma unroll
    for (int mt = 0; mt < 2; mt++) {
        const float* pr = power + (size_t)(rowbase + mt * 16 + l15) * 64;
        A[mt][0] = *(const float4*)(pr + quad * 8);
        A[mt][1] = *(const float4*)(pr + quad * 8 + 4);
        A[mt][2] = *(const float4*)(pr + 32 + quad * 8);
        A[mt][3] = *(const float4*)(pr + 32 + quad * 8 + 4);
    }
    float4 T0[2], T1[2];
#pragma unroll
    for (int mt = 0; mt < 2; mt++) {
        const float* tb = (quad < 2) ? (ele_t + IE[mt] * 16 + quad * 8)
                                     : (azi_t + IA[mt] * 16 + (quad - 2) * 8);
        T0[mt] = *(const float4*)tb;
        T1[mt] = *(const float4*)(tb + 4);
    }

    // ---- prologue: weights -> bf16 LDS; Wv col-sum partials; bv; biases ----
#pragma unroll
    for (int i = 0; i < 6; i++) {
        int idx = tid + i * 1024;            // 6144 elements each
        WqL[idx] = (bf16)Wq[idx];
        WkL[idx] = (bf16)Wk[idx];
    }
    if (tid < 768) {
        int c = tid % 96;
        int g = tid / 96;                    // 0..7, rows g*8..g*8+7
        float s = 0.f;
#pragma unroll
        for (int r = 0; r < 8; r++) s += Wv[(g * 8 + r) * 96 + c];
        pbuf[g * 96 + c] = s;
    } else if (tid < 832) {
        pbuf[768 + (tid - 768)] = bv[tid - 768];
    }
    if (tid < 64) { bqL[tid] = bq[tid]; bkL[tid] = bk[tid]; }
    __syncthreads();                         // BAR1: staging + partials done
    if (tid < 96) {
        float s = 0.f;
#pragma unroll
        for (int g = 0; g < 8; g++) s += pbuf[g * 96 + tid];
        wvs[tid] = s;
    } else if (tid == 96) {
        float s = 0.f;
#pragma unroll
        for (int j = 0; j < 64; j++) s += pbuf[768 + j];
        wvs[96] = s;
    }
    __syncthreads();                         // BAR2: wvs ready (pbuf dead)

    // ---- x fragments (from regs) + fp32 vsum ----
    v4f w0 = *(const v4f*)(wvs + quad * 8);
    v4f w1 = *(const v4f*)(wvs + quad * 8 + 4);
    v4f w2 = *(const v4f*)(wvs + 32 + quad * 8);
    v4f w3 = *(const v4f*)(wvs + 32 + quad * 8 + 4);
    v4f w4 = *(const v4f*)(wvs + 64 + quad * 8);
    v4f w5 = *(const v4f*)(wvs + 64 + quad * 8 + 4);
    const float bvs = wvs[96];

    v8bf xa[2][3];
#pragma unroll
    for (int mt = 0; mt < 2; mt++) {
        xa[mt][0] = pk8(A[mt][0], A[mt][1]);
        xa[mt][1] = pk8(A[mt][2], A[mt][3]);
        xa[mt][2] = pk8(T0[mt], T1[mt]);
        float d = d4(A[mt][0], w0) + d4(A[mt][1], w1) + d4(A[mt][2], w2)
                + d4(A[mt][3], w3) + d4(T0[mt], w4) + d4(T1[mt], w5);
        d += __shfl_xor(d, 16);
        d += __shfl_xor(d, 32);
        if (quad == 0) vsum[wave * 32 + mt * 16 + l15] = d + bvs;
    }

    // ---- Q^T = Wq @ x^T (weights from LDS), fold SCALE, transpose into own Kb region ----
    char* Sw = Kb + wave * 4096;   // this wave's 32 K-rows; used first as Q scratch
#pragma unroll 1
    for (int mtd = 0; mtd < 4; mtd++) {
        const bf16* wrow = WqL + (mtd * 16 + l15) * 96;
        v8bf wq3[3];
#pragma unroll
        for (int kt = 0; kt < 3; kt++)
            wq3[kt] = *(const v8bf*)(wrow + kt * 32 + quad * 8);
        float4 bq4 = *(const float4*)(bqL + mtd * 16 + quad * 4);
#pragma unroll
        for (int ntr = 0; ntr < 2; ntr++) {
            v4f acc = {0.f, 0.f, 0.f, 0.f};
#pragma unroll
            for (int kt = 0; kt < 3; kt++)
                acc = __builtin_amdgcn_mfma_f32_16x16x32_bf16(wq3[kt], xa[ntr][kt], acc, 0, 0, 0);
            int row = ntr * 16 + l15;   // local query
            v4bf o;
            o[0] = (bf16)((acc[0] + bq4.x) * SCALE);
            o[1] = (bf16)((acc[1] + bq4.y) * SCALE);
            o[2] = (bf16)((acc[2] + bq4.z) * SCALE);
            o[3] = (bf16)((acc[3] + bq4.w) * SCALE);
            *(v4bf*)(Sw + row * 128 +
                     ((((mtd * 2 + (quad >> 1)) ^ (row & 7)) << 4) | ((quad & 1) << 3))) = o;
        }
    }
    __syncthreads();                         // BAR_Q: every wave's Q fragments in LDS

    // ---- waves 0-7: read 64 queries' fragments (own group + partner w+8) ----
    v8bf qf[4][2];                           // [g*2+nt][kt]
    if (wave < 8) {
#pragma unroll
        for (int g = 0; g < 2; g++) {
            const char* base = Kb + (wave + 8 * g) * 4096;
#pragma unroll
            for (int nt = 0; nt < 2; nt++)
#pragma unroll
                for (int kt = 0; kt < 2; kt++)
                    qf[g * 2 + nt][kt] = *(const v8bf*)(base + (nt * 16 + l15) * 128 +
                                                        (((kt * 4 + quad) ^ (l15 & 7)) << 4));
        }
    }
    __syncthreads();                         // BAR_Q2: reads done before K overwrites

    // ---- K^T = Wk @ x^T (weights from LDS), overwrite Kb ----
#pragma unroll 1
    for (int mtd = 0; mtd < 4; mtd++) {
        const bf16* wrow = WkL + (mtd * 16 + l15) * 96;
        v8bf wk3[3];
#pragma unroll
        for (int kt = 0; kt < 3; kt++)
            wk3[kt] = *(const v8bf*)(wrow + kt * 32 + quad * 8);
        float4 bk4 = *(const float4*)(bkL + mtd * 16 + quad * 4);
#pragma unroll
        for (int ntr = 0; ntr < 2; ntr++) {
            v4f acc = {0.f, 0.f, 0.f, 0.f};
#pragma unroll
            for (int kt = 0; kt < 3; kt++)
                acc = __builtin_amdgcn_mfma_f32_16x16x32_bf16(wk3[kt], xa[ntr][kt], acc, 0, 0, 0);
            int keyb = wave * 32 + ntr * 16 + l15;
            v4bf o;
            o[0] = (bf16)(acc[0] + bk4.x);
            o[1] = (bf16)(acc[1] + bk4.y);
            o[2] = (bf16)(acc[2] + bk4.z);
            o[3] = (bf16)(acc[3] + bk4.w);
            *(v4bf*)(Kb + keyb * 128 +
                     ((((mtd * 2 + (quad >> 1)) ^ (keyb & 7)) << 4) | ((quad & 1) << 3))) = o;
        }
    }
    __syncthreads();                         // BAR3: K tile + vsum complete

    if (wave >= 8) return;                   // idle waves: no LDS BW consumed

    // ---- Phase B: waves 0-7, 64 queries each over all 512 keys ----
    v2f lacc[4] = {{0.f,0.f},{0.f,0.f},{0.f,0.f},{0.f,0.f}};
    v2f oacc[4] = {{0.f,0.f},{0.f,0.f},{0.f,0.f},{0.f,0.f}};
#pragma unroll 1
    for (int t = 0; t < 16; t++) {
        v8bf kf[2][2];
#pragma unroll
        for (int mtk = 0; mtk < 2; mtk++)
#pragma unroll
            for (int kt = 0; kt < 2; kt++) {
                int key = t * 32 + mtk * 16 + l15;
                kf[mtk][kt] = *(const v8bf*)(Kb + key * 128 + (((kt * 4 + quad) ^ (key & 7)) << 4));
            }
        v4f vs[2];
#pragma unroll
        for (int mtk = 0; mtk < 2; mtk++)
            vs[mtk] = *(const v4f*)(vsum + t * 32 + mtk * 16 + quad * 4);   // quad-broadcast
#pragma unroll
        for (int mtk = 0; mtk < 2; mtk++) {
            v2f v01 = {vs[mtk][0], vs[mtk][1]};
            v2f v23 = {vs[mtk][2], vs[mtk][3]};
#pragma unroll
            for (int qg = 0; qg < 4; qg++) {
                v4f acc = {0.f, 0.f, 0.f, 0.f};
                acc = __builtin_amdgcn_mfma_f32_16x16x32_bf16(kf[mtk][0], qf[qg][0], acc, 0, 0, 0);
                acc = __builtin_amdgcn_mfma_f32_16x16x32_bf16(kf[mtk][1], qf[qg][1], acc, 0, 0, 0);
                v2f p01 = {__builtin_amdgcn_exp2f(acc[0]), __builtin_amdgcn_exp2f(acc[1])};
                v2f p23 = {__builtin_amdgcn_exp2f(acc[2]), __builtin_amdgcn_exp2f(acc[3])};
                lacc[qg] += p01 + p23;               // v_pk_add_f32
                oacc[qg] += p01 * v01 + p23 * v23;   // v_pk_fma_f32
            }
        }
    }

    // ---- epilogue: reduce over key-quads, out = osum/lsum ----
#pragma unroll
    for (int qg = 0; qg < 4; qg++) {
        float lv = lacc[qg][0] + lacc[qg][1];
        lv += __shfl_xor(lv, 16);
        lv += __shfl_xor(lv, 32);
        float ov = oacc[qg][0] + oacc[qg][1];
        ov += __shfl_xor(ov, 16);
        ov += __shfl_xor(ov, 32);
        if (quad == 0) {
            int row = blockIdx.x * 512 + (wave + 8 * (qg >> 1)) * 32 + (qg & 1) * 16 + l15;
            out[row] = ov / lv;
        }
    }
}

extern "C" void kernel_launch(void* const* d_in, const int* in_sizes, int n_in,
                              void* d_out, int out_size, void* d_ws, size_t ws_size,
                              hipStream_t stream) {
    const float* power = (const float*)d_in[0];
    const int*   ele_i = (const int*)d_in[1];
    // d_in[2] = range_indices: unused by the reference (positional reshape)
    const int*   azi_i = (const int*)d_in[3];
    const float* ele_t = (const float*)d_in[4];
    const float* azi_t = (const float*)d_in[5];
    const float* Wq = (const float*)d_in[6];
    const float* bq = (const float*)d_in[7];
    const float* Wk = (const float*)d_in[8];
    const float* bk = (const float*)d_in[9];
    const float* Wv = (const float*)d_in[10];
    const float* bv = (const float*)d_in[11];
    float* out = (float*)d_out;

    // Kb 64K + vsum 2K + wvs 512B + WqL 12K + WkL 12K + bqL 256B + bkL 256B
    const int lds_bytes = 93184;
    (void)hipFuncSetAttribute(reinterpret_cast<const void*>(sda_kernel),
                              hipFuncAttributeMaxDynamicSharedMemorySize, lds_bytes);
    sda_kernel<<<256, 1024, lds_bytes, stream>>>(power, ele_i, azi_i, ele_t, azi_t,
                                                 Wq, bq, Wk, bk, Wv, bv, out);
}